// Round 4
// baseline (75.253 us; speedup 1.0000x reference)
//
#include <hip/hip_runtime.h>

// Chamfer loss: B=8, N1=N2=4096, D=3, fp32 in, scalar fp32 out.
// R4: plain-fma pipe saturation. v_pk_fma_f32 was a null (fp32 pipe peak =
// plain v_fma rate on gfx950). Floor = 3.5 VALU insts/pair:
//   s_j = h_j - p.y_j (3 fma), min3(s_even, s_odd, acc) (0.5/pair).
// TROWS=8 consecutive rows/thread (float4 row loads, 1 LDS b128 : 28 VALU),
// launch_bounds(256,4) for a 128-VGPR prefetch window.

namespace {
constexpr int Bc = 8;
constexpr int Nc = 4096;
constexpr int TPB = 256;
constexpr int TROWS = 8;                      // consecutive rows per thread
constexpr int ROWS_PER_BLOCK = TPB * TROWS;   // 2048
constexpr int JCHUNK = 128;                   // other-points staged per block
constexpr int NJCH = Nc / JCHUNK;             // 32
constexpr int NRB  = Nc / ROWS_PER_BLOCK;     // 2
constexpr unsigned INF_BITS = 0x7f800000u;
}

__device__ __forceinline__ float min3f(float a, float b, float c) {
  float d;
  asm("v_min3_f32 %0, %1, %2, %3" : "=v"(d) : "v"(a), "v"(b), "v"(c));
  return d;
}

// Persistent scratch (re-initialized every call -> deterministic).
__device__ unsigned int g_mins[2 * Bc * Nc];

__global__ __launch_bounds__(TPB) void init_kernel(float* out) {
  int i = blockIdx.x * TPB + threadIdx.x;
  if (i < 2 * Bc * Nc) g_mins[i] = INF_BITS;
  if (i == 0) out[0] = 0.0f;
}

__global__ __launch_bounds__(TPB, 4) void cham_kernel(const float* __restrict__ pred,
                                                      const float* __restrict__ gt) {
  const int bx     = blockIdx.x;        // [0, NRB*NJCH)
  const int rowblk = bx / NJCH;
  const int jblk   = bx % NJCH;
  const int b      = blockIdx.y;
  const int dir    = blockIdx.z;        // 0: rows=pred vs gt; 1: rows=gt vs pred

  const float* rows    = (dir == 0) ? pred : gt;
  const float* others  = (dir == 0) ? gt : pred;
  const float* rowbase = rows   + ((size_t)b * Nc + (size_t)rowblk * ROWS_PER_BLOCK) * 3;
  const float* othbase = others + ((size_t)b * Nc + (size_t)jblk * JCHUNK) * 3;
  unsigned int* minbase = g_mins + ((size_t)dir * Bc + b) * Nc + (size_t)rowblk * ROWS_PER_BLOCK;

  __shared__ __align__(16) float4 pts[JCHUNK];   // (x, y, z, 0.5*||y||^2)

  const int t = threadIdx.x;
  if (t < JCHUNK) {
    const float* p = othbase + 3 * t;
    float x = p[0], y = p[1], z = p[2];
    float h = 0.5f * (x * x + y * y + z * z);
    pts[t] = make_float4(x, y, z, h);
  }

  // 8 consecutive rows per thread: 24 floats = 6 aligned float4 loads.
  const float4* rp = (const float4*)(rowbase + 24 * (size_t)t);
  float4 f0 = rp[0], f1 = rp[1], f2 = rp[2], f3 = rp[3], f4 = rp[4], f5 = rp[5];
  float rx[TROWS] = {f0.x, f0.w, f1.z, f2.y, f3.x, f3.w, f4.z, f5.y};
  float ry[TROWS] = {f0.y, f1.x, f1.w, f2.z, f3.y, f4.x, f4.w, f5.z};
  float rz[TROWS] = {f0.z, f1.y, f2.x, f2.w, f3.z, f4.y, f5.x, f5.w};

  float nx[TROWS], ny[TROWS], nz[TROWS], p2[TROWS], acc[TROWS];
  #pragma unroll
  for (int r = 0; r < TROWS; ++r) {
    nx[r] = -rx[r]; ny[r] = -ry[r]; nz[r] = -rz[r];
    p2[r] = rx[r] * rx[r] + ry[r] * ry[r] + rz[r] * rz[r];
    acc[r] = __builtin_inff();
  }
  __syncthreads();

  #pragma unroll 4
  for (int j = 0; j < JCHUNK; j += 2) {
    const float4 P0 = pts[j];       // uniform-address broadcast, conflict-free
    const float4 P1 = pts[j + 1];
    #pragma unroll
    for (int r = 0; r < TROWS; ++r) {
      float s0 = fmaf(nx[r], P0.x, fmaf(ny[r], P0.y, fmaf(nz[r], P0.z, P0.w)));
      float s1 = fmaf(nx[r], P1.x, fmaf(ny[r], P1.y, fmaf(nz[r], P1.z, P1.w)));
      acc[r] = min3f(s0, s1, acc[r]);
    }
  }

  #pragma unroll
  for (int r = 0; r < TROWS; ++r) {
    float d2 = fmaf(2.0f, acc[r], p2[r]);   // ||p||^2 + ||y||^2 - 2 p.y
    d2 = fmaxf(d2, 0.0f);                   // clamp (monotone = per-pair clamp)
    atomicMin(minbase + TROWS * t + r, __float_as_uint(d2));
  }
}

__global__ __launch_bounds__(TPB) void reduce_kernel(float* __restrict__ out) {
  const int total = 2 * Bc * Nc;
  float s = 0.0f;
  for (int i = blockIdx.x * TPB + threadIdx.x; i < total; i += gridDim.x * TPB)
    s += __uint_as_float(g_mins[i]);
  #pragma unroll
  for (int off = 32; off > 0; off >>= 1) s += __shfl_down(s, off, 64);
  __shared__ float wsum[TPB / 64];
  const int lane = threadIdx.x & 63;
  const int wid  = threadIdx.x >> 6;
  if (lane == 0) wsum[wid] = s;
  __syncthreads();
  if (threadIdx.x == 0) {
    float tot = 0.0f;
    #pragma unroll
    for (int w = 0; w < TPB / 64; ++w) tot += wsum[w];
    atomicAdd(out, tot * (1.0f / (float)(Bc * Nc)));
  }
}

extern "C" void kernel_launch(void* const* d_in, const int* in_sizes, int n_in,
                              void* d_out, int out_size, void* d_ws, size_t ws_size,
                              hipStream_t stream) {
  const float* pred = (const float*)d_in[0];
  const float* gt   = (const float*)d_in[1];
  float* out = (float*)d_out;

  init_kernel<<<(2 * Bc * Nc + TPB - 1) / TPB, TPB, 0, stream>>>(out);

  dim3 grid(NRB * NJCH, Bc, 2);   // 64 x 8 x 2 = 1024 blocks
  cham_kernel<<<grid, TPB, 0, stream>>>(pred, gt);

  reduce_kernel<<<64, TPB, 0, stream>>>(out);
}

// Round 7
// 43.839 us; speedup vs baseline: 1.7166x; 1.7166x over previous
//
#include <hip/hip_runtime.h>

// Chamfer loss via MFMA (R7): cross-term-only MFMA + exact fp32 norms.
// D = -2 p.g from v_mfma_f32_16x16x32_bf16 with hi/lo bf16 payload:
//   A: [ah(3) al(3) ah(3) al(3) 0(4)]   (a = -p)
//   B: [bh(3) bh(3) bl(3) bl(3) 0(4)]   (b = g)
//   P.Q = (ah+al).(bh+bl) = a.g ;  K-half replication -> D = 2 P.Q = -2 p.g.
// d2 = D + p2[row] + g2[col] added in fp32 per element (norm K-slots removed
// -- R6's prime suspect). Row/col indices use the m89-verified C/D map
// (col=lane&15, row=(lane>>4)*4+reg); if that map is wrong, norms land on
// wrong elements and the error goes O(1) -- loud, diagnosable.
// Reduction code kept byte-identical to R6 (controlled variable).

namespace {
constexpr int Bc = 8, Nc = 4096, TPB = 256;
constexpr int TILE = 256;             // rows & cols per block
constexpr int NT = Nc / TILE;         // 16
constexpr unsigned INF_BITS = 0x7f800000u;
}

typedef short bf16x8 __attribute__((ext_vector_type(8)));
typedef float f32x4 __attribute__((ext_vector_type(4)));

__device__ unsigned g_min2[2 * Bc * Nc];        // row mins | col mins
__device__ unsigned short g_apk[Bc * Nc * 16];  // packed pred payload, 1 MB
__device__ unsigned short g_bpk[Bc * Nc * 16];  // packed gt payload, 1 MB
__device__ float g_p2[Bc * Nc];                 // |p|^2 fp32
__device__ float g_g2[Bc * Nc];                 // |g|^2 fp32

__device__ __forceinline__ unsigned short f2bf(float f) {  // RNE f32->bf16
  unsigned u = __float_as_uint(f);
  return (unsigned short)((u + 0x7FFFu + ((u >> 16) & 1u)) >> 16);
}
__device__ __forceinline__ float bf2f(unsigned short h) {
  return __uint_as_float(((unsigned)h) << 16);
}
__device__ __forceinline__ float min3f(float a, float b, float c) {
  float d;
  asm("v_min3_f32 %0, %1, %2, %3" : "=v"(d) : "v"(a), "v"(b), "v"(c));
  return d;
}

__global__ __launch_bounds__(TPB) void init_kernel(float* out) {
  int i = blockIdx.x * TPB + threadIdx.x;
  if (i < 2 * Bc * Nc) g_min2[i] = INF_BITS;
  if (i == 0) out[0] = 0.0f;
}

__global__ __launch_bounds__(TPB) void pack_kernel(const float* __restrict__ pred,
                                                   const float* __restrict__ gt) {
  const int idx  = blockIdx.x * TPB + threadIdx.x;   // [0, 2*B*N)
  const int side = idx >> 15;                        // B*N = 32768
  const int p    = idx & (Bc * Nc - 1);
  const float* src = side ? gt : pred;
  float x = src[3 * p], y = src[3 * p + 1], z = src[3 * p + 2];
  float n2 = x * x + y * y + z * z;

  float sx = side ? x : -x, sy = side ? y : -y, sz = side ? z : -z;
  unsigned short hx = f2bf(sx), hy = f2bf(sy), hz = f2bf(sz);
  unsigned short lx = f2bf(sx - bf2f(hx)), ly = f2bf(sy - bf2f(hy)), lz = f2bf(sz - bf2f(hz));

  unsigned short s[16];
  if (side == 0) {   // A: [ah al ah al]  (alternating h/l 3-blocks)
    s[0]=hx; s[1]=hy; s[2]=hz;   s[3]=lx; s[4]=ly; s[5]=lz;
    s[6]=hx; s[7]=hy; s[8]=hz;   s[9]=lx; s[10]=ly; s[11]=lz;
    g_p2[p] = n2;
  } else {           // B: [bh bh bl bl]
    s[0]=hx; s[1]=hy; s[2]=hz;   s[3]=hx; s[4]=hy; s[5]=hz;
    s[6]=lx; s[7]=ly; s[8]=lz;   s[9]=lx; s[10]=ly; s[11]=lz;
    g_g2[p] = n2;
  }
  s[12] = 0; s[13] = 0; s[14] = 0; s[15] = 0;

  uint4 u0, u1;
  u0.x = (unsigned)s[0]  | ((unsigned)s[1]  << 16);
  u0.y = (unsigned)s[2]  | ((unsigned)s[3]  << 16);
  u0.z = (unsigned)s[4]  | ((unsigned)s[5]  << 16);
  u0.w = (unsigned)s[6]  | ((unsigned)s[7]  << 16);
  u1.x = (unsigned)s[8]  | ((unsigned)s[9]  << 16);
  u1.y = (unsigned)s[10] | ((unsigned)s[11] << 16);
  u1.z = (unsigned)s[12] | ((unsigned)s[13] << 16);
  u1.w = (unsigned)s[14] | ((unsigned)s[15] << 16);
  uint4* dst = (uint4*)((side ? g_bpk : g_apk) + (size_t)p * 16);
  dst[0] = u0; dst[1] = u1;
}

__global__ __launch_bounds__(TPB, 2) void cham_mfma() {
  const int ct = blockIdx.x, rt = blockIdx.y, b = blockIdx.z;
  const int t = threadIdx.x, lane = t & 63, w = t >> 6;
  const int l15 = lane & 15, lg = lane >> 4;     // lane group 0..3
  const int ksel = (lg & 1) * 8;                 // payload half (replicated)

  const int row0 = rt * TILE + w * 64;           // wave's 64-row stripe
  const int col0 = ct * TILE;

  const unsigned short* Ap = g_apk + (size_t)b * Nc * 16;
  const unsigned short* Bp = g_bpk + (size_t)b * Nc * 16;
  const float* P2 = g_p2 + (size_t)b * Nc;
  const float* G2 = g_g2 + (size_t)b * Nc;

  bf16x8 afr[4];
  float p2r[4][4];
  #pragma unroll
  for (int ai = 0; ai < 4; ++ai) {
    afr[ai] = *(const bf16x8*)(Ap + (size_t)(row0 + ai * 16 + l15) * 16 + ksel);
    #pragma unroll
    for (int r = 0; r < 4; ++r)
      p2r[ai][r] = P2[row0 + ai * 16 + lg * 4 + r];   // verified C/D row map
  }
  bf16x8 bfr[16];
  float g2c[16];
  #pragma unroll
  for (int bi = 0; bi < 16; ++bi) {
    bfr[bi] = *(const bf16x8*)(Bp + (size_t)(col0 + bi * 16 + l15) * 16 + ksel);
    g2c[bi] = G2[col0 + bi * 16 + l15];               // verified C/D col map
  }

  const f32x4 zero = {0, 0, 0, 0};
  const float INF = __builtin_inff();
  float racc[4][4], cacc[16];
  #pragma unroll
  for (int ai = 0; ai < 4; ++ai)
    #pragma unroll
    for (int r = 0; r < 4; ++r) racc[ai][r] = INF;
  #pragma unroll
  for (int bi = 0; bi < 16; ++bi) cacc[bi] = INF;

  #pragma unroll
  for (int bi = 0; bi < 16; ++bi) {
    #pragma unroll
    for (int ai = 0; ai < 4; ++ai) {
      f32x4 d = __builtin_amdgcn_mfma_f32_16x16x32_bf16(afr[ai], bfr[bi], zero, 0, 0, 0);
      // row path: min_j (D + g2[j]); p2 added once after the fold
      racc[ai][0] = fminf(racc[ai][0], d[0] + g2c[bi]);
      racc[ai][1] = fminf(racc[ai][1], d[1] + g2c[bi]);
      racc[ai][2] = fminf(racc[ai][2], d[2] + g2c[bi]);
      racc[ai][3] = fminf(racc[ai][3], d[3] + g2c[bi]);
      // col path: min_i (D + p2[i]); g2 added once after the fold
      cacc[bi] = min3f(d[0] + p2r[ai][0], d[1] + p2r[ai][1], cacc[bi]);
      cacc[bi] = min3f(d[2] + p2r[ai][2], d[3] + p2r[ai][3], cacc[bi]);
    }
  }

  // ---- row mins: reduce across 16 cols (lanes sharing lg) ----
  #pragma unroll
  for (int ai = 0; ai < 4; ++ai) {
    #pragma unroll
    for (int r = 0; r < 4; ++r) {
      float v = racc[ai][r];
      v = fminf(v, __shfl_xor(v, 1, 64));
      v = fminf(v, __shfl_xor(v, 2, 64));
      v = fminf(v, __shfl_xor(v, 4, 64));
      v = fminf(v, __shfl_xor(v, 8, 64));
      racc[ai][r] = v;
    }
  }
  if (l15 == 0) {
    unsigned* grow = g_min2 + (size_t)b * Nc + row0;
    #pragma unroll
    for (int ai = 0; ai < 4; ++ai) {
      #pragma unroll
      for (int r = 0; r < 4; ++r) {
        float v = fmaxf(racc[ai][r] + p2r[ai][r], 0.0f);  // + |p|^2, clamp
        atomicMin(grow + ai * 16 + lg * 4 + r, __float_as_uint(v));
      }
    }
  }

  // ---- col mins: fold lane groups, combine 4 waves via LDS ----
  __shared__ float lcol[4][TILE];
  #pragma unroll
  for (int bi = 0; bi < 16; ++bi) {
    float v = cacc[bi];
    v = fminf(v, __shfl_xor(v, 16, 64));
    v = fminf(v, __shfl_xor(v, 32, 64));
    v = v + g2c[bi];                                   // + |g|^2
    if (lane < 16) lcol[w][bi * 16 + l15] = v;
  }
  __syncthreads();
  {
    float v = fminf(fminf(lcol[0][t], lcol[1][t]), fminf(lcol[2][t], lcol[3][t]));
    v = fmaxf(v, 0.0f);                                // clamp BEFORE unsigned min
    atomicMin(g_min2 + (size_t)(Bc + b) * Nc + col0 + t, __float_as_uint(v));
  }
}

__global__ __launch_bounds__(TPB) void reduce_kernel(float* __restrict__ out) {
  const int total = 2 * Bc * Nc;
  float s = 0.0f;
  for (int i = blockIdx.x * TPB + threadIdx.x; i < total; i += gridDim.x * TPB)
    s += __uint_as_float(g_min2[i]);          // already clamped non-negative
  #pragma unroll
  for (int off = 32; off > 0; off >>= 1) s += __shfl_down(s, off, 64);
  __shared__ float wsum[TPB / 64];
  const int lane = threadIdx.x & 63, wid = threadIdx.x >> 6;
  if (lane == 0) wsum[wid] = s;
  __syncthreads();
  if (threadIdx.x == 0) {
    float tot = 0.0f;
    #pragma unroll
    for (int w = 0; w < TPB / 64; ++w) tot += wsum[w];
    atomicAdd(out, tot * (1.0f / (float)(Bc * Nc)));
  }
}

extern "C" void kernel_launch(void* const* d_in, const int* in_sizes, int n_in,
                              void* d_out, int out_size, void* d_ws, size_t ws_size,
                              hipStream_t stream) {
  const float* pred = (const float*)d_in[0];
  const float* gt   = (const float*)d_in[1];
  float* out = (float*)d_out;

  init_kernel<<<(2 * Bc * Nc + TPB - 1) / TPB, TPB, 0, stream>>>(out);
  pack_kernel<<<(2 * Bc * Nc) / TPB, TPB, 0, stream>>>(pred, gt);

  dim3 grid(NT, NT, Bc);   // 16 x 16 x 8 = 2048 blocks
  cham_mfma<<<grid, TPB, 0, stream>>>();

  reduce_kernel<<<64, TPB, 0, stream>>>(out);
}

// Round 9
// 40.559 us; speedup vs baseline: 1.8554x; 1.0809x over previous
//
#include <hip/hip_runtime.h>

// Chamfer loss via MFMA (R9): R7-exact math, scheduling-only changes.
// R7 is the known-exact anchor (absmax 0.0). R6/R8 showed extra-payload and
// C-operand variants fail unexplained -> banned. Changes vs R7:
//   1. bfr in 4 groups of 4 -> VGPR ~116, __launch_bounds__(256,4): 4 waves/SIMD
//   2. row fold as paired min3 (fp min reorders are bit-exact): 14->12 VALU/MFMA
//   3. everything else byte-identical to R7 (init/pack/cham/reduce).

namespace {
constexpr int Bc = 8, Nc = 4096, TPB = 256;
constexpr int TILE = 256;             // rows & cols per block
constexpr int NT = Nc / TILE;         // 16
constexpr unsigned INF_BITS = 0x7f800000u;
}

typedef short bf16x8 __attribute__((ext_vector_type(8)));
typedef float f32x4 __attribute__((ext_vector_type(4)));

__device__ unsigned g_min2[2 * Bc * Nc];        // row mins | col mins
__device__ unsigned short g_apk[Bc * Nc * 16];  // packed pred payload, 1 MB
__device__ unsigned short g_bpk[Bc * Nc * 16];  // packed gt payload, 1 MB
__device__ float g_p2[Bc * Nc];                 // |p|^2 fp32
__device__ float g_g2[Bc * Nc];                 // |g|^2 fp32

__device__ __forceinline__ unsigned short f2bf(float f) {  // RNE f32->bf16
  unsigned u = __float_as_uint(f);
  return (unsigned short)((u + 0x7FFFu + ((u >> 16) & 1u)) >> 16);
}
__device__ __forceinline__ float bf2f(unsigned short h) {
  return __uint_as_float(((unsigned)h) << 16);
}
__device__ __forceinline__ float min3f(float a, float b, float c) {
  float d;
  asm("v_min3_f32 %0, %1, %2, %3" : "=v"(d) : "v"(a), "v"(b), "v"(c));
  return d;
}

__global__ __launch_bounds__(TPB) void init_kernel(float* out) {
  int i = blockIdx.x * TPB + threadIdx.x;
  if (i < 2 * Bc * Nc) g_min2[i] = INF_BITS;
  if (i == 0) out[0] = 0.0f;
}

__global__ __launch_bounds__(TPB) void pack_kernel(const float* __restrict__ pred,
                                                   const float* __restrict__ gt) {
  const int idx  = blockIdx.x * TPB + threadIdx.x;   // [0, 2*B*N)
  const int side = idx >> 15;                        // B*N = 32768
  const int p    = idx & (Bc * Nc - 1);
  const float* src = side ? gt : pred;
  float x = src[3 * p], y = src[3 * p + 1], z = src[3 * p + 2];
  float n2 = x * x + y * y + z * z;

  float sx = side ? x : -x, sy = side ? y : -y, sz = side ? z : -z;
  unsigned short hx = f2bf(sx), hy = f2bf(sy), hz = f2bf(sz);
  unsigned short lx = f2bf(sx - bf2f(hx)), ly = f2bf(sy - bf2f(hy)), lz = f2bf(sz - bf2f(hz));

  unsigned short s[16];
  if (side == 0) {   // A: [ah al ah al]  (alternating h/l 3-blocks)
    s[0]=hx; s[1]=hy; s[2]=hz;   s[3]=lx; s[4]=ly; s[5]=lz;
    s[6]=hx; s[7]=hy; s[8]=hz;   s[9]=lx; s[10]=ly; s[11]=lz;
    g_p2[p] = n2;
  } else {           // B: [bh bh bl bl]
    s[0]=hx; s[1]=hy; s[2]=hz;   s[3]=hx; s[4]=hy; s[5]=hz;
    s[6]=lx; s[7]=ly; s[8]=lz;   s[9]=lx; s[10]=ly; s[11]=lz;
    g_g2[p] = n2;
  }
  s[12] = 0; s[13] = 0; s[14] = 0; s[15] = 0;

  uint4 u0, u1;
  u0.x = (unsigned)s[0]  | ((unsigned)s[1]  << 16);
  u0.y = (unsigned)s[2]  | ((unsigned)s[3]  << 16);
  u0.z = (unsigned)s[4]  | ((unsigned)s[5]  << 16);
  u0.w = (unsigned)s[6]  | ((unsigned)s[7]  << 16);
  u1.x = (unsigned)s[8]  | ((unsigned)s[9]  << 16);
  u1.y = (unsigned)s[10] | ((unsigned)s[11] << 16);
  u1.z = (unsigned)s[12] | ((unsigned)s[13] << 16);
  u1.w = (unsigned)s[14] | ((unsigned)s[15] << 16);
  uint4* dst = (uint4*)((side ? g_bpk : g_apk) + (size_t)p * 16);
  dst[0] = u0; dst[1] = u1;
}

__global__ __launch_bounds__(TPB, 4) void cham_mfma() {
  const int ct = blockIdx.x, rt = blockIdx.y, b = blockIdx.z;
  const int t = threadIdx.x, lane = t & 63, w = t >> 6;
  const int l15 = lane & 15, lg = lane >> 4;     // lane group 0..3
  const int ksel = (lg & 1) * 8;                 // payload half

  const int row0 = rt * TILE + w * 64;           // wave's 64-row stripe
  const int col0 = ct * TILE;

  const unsigned short* Ap = g_apk + (size_t)b * Nc * 16;
  const unsigned short* Bp = g_bpk + (size_t)b * Nc * 16;
  const float* P2 = g_p2 + (size_t)b * Nc;
  const float* G2 = g_g2 + (size_t)b * Nc;

  bf16x8 afr[4];
  float p2r[4][4];
  #pragma unroll
  for (int ai = 0; ai < 4; ++ai) {
    afr[ai] = *(const bf16x8*)(Ap + (size_t)(row0 + ai * 16 + l15) * 16 + ksel);
    #pragma unroll
    for (int r = 0; r < 4; ++r)
      p2r[ai][r] = P2[row0 + ai * 16 + lg * 4 + r];   // verified C/D row map
  }
  float g2c[16];
  #pragma unroll
  for (int bi = 0; bi < 16; ++bi)
    g2c[bi] = G2[col0 + bi * 16 + l15];               // verified C/D col map

  const f32x4 zero = {0, 0, 0, 0};
  const float INF = __builtin_inff();
  float racc[4][4], cacc[16];
  #pragma unroll
  for (int ai = 0; ai < 4; ++ai)
    #pragma unroll
    for (int r = 0; r < 4; ++r) racc[ai][r] = INF;
  #pragma unroll
  for (int bi = 0; bi < 16; ++bi) cacc[bi] = INF;

  #pragma unroll
  for (int grp = 0; grp < 4; ++grp) {
    bf16x8 bfr[4];
    #pragma unroll
    for (int k = 0; k < 4; ++k)
      bfr[k] = *(const bf16x8*)(Bp + (size_t)(col0 + (grp * 4 + k) * 16 + l15) * 16 + ksel);
    #pragma unroll
    for (int kp = 0; kp < 2; ++kp) {
      const int bi0 = grp * 4 + kp * 2, bi1 = bi0 + 1;
      #pragma unroll
      for (int ai = 0; ai < 4; ++ai) {
        f32x4 d0 = __builtin_amdgcn_mfma_f32_16x16x32_bf16(afr[ai], bfr[kp * 2],     zero, 0, 0, 0);
        f32x4 d1 = __builtin_amdgcn_mfma_f32_16x16x32_bf16(afr[ai], bfr[kp * 2 + 1], zero, 0, 0, 0);
        // row path: min_j (D + g2[j]) — paired min3, bit-exact reorder of R7
        racc[ai][0] = min3f(d0[0] + g2c[bi0], d1[0] + g2c[bi1], racc[ai][0]);
        racc[ai][1] = min3f(d0[1] + g2c[bi0], d1[1] + g2c[bi1], racc[ai][1]);
        racc[ai][2] = min3f(d0[2] + g2c[bi0], d1[2] + g2c[bi1], racc[ai][2]);
        racc[ai][3] = min3f(d0[3] + g2c[bi0], d1[3] + g2c[bi1], racc[ai][3]);
        // col path: min_i (D + p2[i]) — as R7
        cacc[bi0] = min3f(d0[0] + p2r[ai][0], d0[1] + p2r[ai][1], cacc[bi0]);
        cacc[bi0] = min3f(d0[2] + p2r[ai][2], d0[3] + p2r[ai][3], cacc[bi0]);
        cacc[bi1] = min3f(d1[0] + p2r[ai][0], d1[1] + p2r[ai][1], cacc[bi1]);
        cacc[bi1] = min3f(d1[2] + p2r[ai][2], d1[3] + p2r[ai][3], cacc[bi1]);
      }
    }
  }

  // ---- row mins: reduce across 16 cols (lanes sharing lg) ----
  #pragma unroll
  for (int ai = 0; ai < 4; ++ai) {
    #pragma unroll
    for (int r = 0; r < 4; ++r) {
      float v = racc[ai][r];
      v = fminf(v, __shfl_xor(v, 1, 64));
      v = fminf(v, __shfl_xor(v, 2, 64));
      v = fminf(v, __shfl_xor(v, 4, 64));
      v = fminf(v, __shfl_xor(v, 8, 64));
      racc[ai][r] = v;
    }
  }
  if (l15 == 0) {
    unsigned* grow = g_min2 + (size_t)b * Nc + row0;
    #pragma unroll
    for (int ai = 0; ai < 4; ++ai) {
      #pragma unroll
      for (int r = 0; r < 4; ++r) {
        float v = fmaxf(racc[ai][r] + p2r[ai][r], 0.0f);  // + |p|^2, clamp
        atomicMin(grow + ai * 16 + lg * 4 + r, __float_as_uint(v));
      }
    }
  }

  // ---- col mins: fold lane groups, combine 4 waves via LDS ----
  __shared__ float lcol[4][TILE];
  #pragma unroll
  for (int bi = 0; bi < 16; ++bi) {
    float v = cacc[bi];
    v = fminf(v, __shfl_xor(v, 16, 64));
    v = fminf(v, __shfl_xor(v, 32, 64));
    v = v + g2c[bi];                                   // + |g|^2
    if (lane < 16) lcol[w][bi * 16 + l15] = v;
  }
  __syncthreads();
  {
    float v = fminf(fminf(lcol[0][t], lcol[1][t]), fminf(lcol[2][t], lcol[3][t]));
    v = fmaxf(v, 0.0f);                                // clamp BEFORE unsigned min
    atomicMin(g_min2 + (size_t)(Bc + b) * Nc + col0 + t, __float_as_uint(v));
  }
}

__global__ __launch_bounds__(TPB) void reduce_kernel(float* __restrict__ out) {
  const int total = 2 * Bc * Nc;
  float s = 0.0f;
  for (int i = blockIdx.x * TPB + threadIdx.x; i < total; i += gridDim.x * TPB)
    s += __uint_as_float(g_min2[i]);          // already clamped non-negative
  #pragma unroll
  for (int off = 32; off > 0; off >>= 1) s += __shfl_down(s, off, 64);
  __shared__ float wsum[TPB / 64];
  const int lane = threadIdx.x & 63, wid = threadIdx.x >> 6;
  if (lane == 0) wsum[wid] = s;
  __syncthreads();
  if (threadIdx.x == 0) {
    float tot = 0.0f;
    #pragma unroll
    for (int w = 0; w < TPB / 64; ++w) tot += wsum[w];
    atomicAdd(out, tot * (1.0f / (float)(Bc * Nc)));
  }
}

extern "C" void kernel_launch(void* const* d_in, const int* in_sizes, int n_in,
                              void* d_out, int out_size, void* d_ws, size_t ws_size,
                              hipStream_t stream) {
  const float* pred = (const float*)d_in[0];
  const float* gt   = (const float*)d_in[1];
  float* out = (float*)d_out;

  init_kernel<<<(2 * Bc * Nc + TPB - 1) / TPB, TPB, 0, stream>>>(out);
  pack_kernel<<<(2 * Bc * Nc) / TPB, TPB, 0, stream>>>(pred, gt);

  dim3 grid(NT, NT, Bc);   // 16 x 16 x 8 = 2048 blocks
  cham_mfma<<<grid, TPB, 0, stream>>>();

  reduce_kernel<<<64, TPB, 0, stream>>>(out);
}

// Round 10
// 39.995 us; speedup vs baseline: 1.8816x; 1.0141x over previous
//
#include <hip/hip_runtime.h>

// Chamfer loss via MFMA (R10): R9 + LDS staging of A/B tiles (one change).
// R9 post-mortem: cham was L2-BW-bound (~640 MB L2 stream ~= 19 us), not
// VALU-bound. Stage the block-shared B-tile (8KB), A-tile (8KB), g2 (1KB)
// in LDS once; 4 waves reuse them. L2 traffic /16, stream moves to LDS
// (~2.1 us at 78 TB/s). Math/folds/maps/atomics byte-identical to R9.
// LDS layout [khalf][col][8shorts]: ds_write & ds_read both 2-way/free.

namespace {
constexpr int Bc = 8, Nc = 4096, TPB = 256;
constexpr int TILE = 256;             // rows & cols per block
constexpr int NT = Nc / TILE;         // 16
constexpr unsigned INF_BITS = 0x7f800000u;
}

typedef short bf16x8 __attribute__((ext_vector_type(8)));
typedef float f32x4 __attribute__((ext_vector_type(4)));

__device__ unsigned g_min2[2 * Bc * Nc];        // row mins | col mins
__device__ unsigned short g_apk[Bc * Nc * 16];  // packed pred payload, 1 MB
__device__ unsigned short g_bpk[Bc * Nc * 16];  // packed gt payload, 1 MB
__device__ float g_p2[Bc * Nc];                 // |p|^2 fp32
__device__ float g_g2[Bc * Nc];                 // |g|^2 fp32

__device__ __forceinline__ unsigned short f2bf(float f) {  // RNE f32->bf16
  unsigned u = __float_as_uint(f);
  return (unsigned short)((u + 0x7FFFu + ((u >> 16) & 1u)) >> 16);
}
__device__ __forceinline__ float bf2f(unsigned short h) {
  return __uint_as_float(((unsigned)h) << 16);
}
__device__ __forceinline__ float min3f(float a, float b, float c) {
  float d;
  asm("v_min3_f32 %0, %1, %2, %3" : "=v"(d) : "v"(a), "v"(b), "v"(c));
  return d;
}

__global__ __launch_bounds__(TPB) void init_kernel(float* out) {
  int i = blockIdx.x * TPB + threadIdx.x;
  if (i < 2 * Bc * Nc) g_min2[i] = INF_BITS;
  if (i == 0) out[0] = 0.0f;
}

__global__ __launch_bounds__(TPB) void pack_kernel(const float* __restrict__ pred,
                                                   const float* __restrict__ gt) {
  const int idx  = blockIdx.x * TPB + threadIdx.x;   // [0, 2*B*N)
  const int side = idx >> 15;                        // B*N = 32768
  const int p    = idx & (Bc * Nc - 1);
  const float* src = side ? gt : pred;
  float x = src[3 * p], y = src[3 * p + 1], z = src[3 * p + 2];
  float n2 = x * x + y * y + z * z;

  float sx = side ? x : -x, sy = side ? y : -y, sz = side ? z : -z;
  unsigned short hx = f2bf(sx), hy = f2bf(sy), hz = f2bf(sz);
  unsigned short lx = f2bf(sx - bf2f(hx)), ly = f2bf(sy - bf2f(hy)), lz = f2bf(sz - bf2f(hz));

  unsigned short s[16];
  if (side == 0) {   // A: [ah al ah al]  (alternating h/l 3-blocks)
    s[0]=hx; s[1]=hy; s[2]=hz;   s[3]=lx; s[4]=ly; s[5]=lz;
    s[6]=hx; s[7]=hy; s[8]=hz;   s[9]=lx; s[10]=ly; s[11]=lz;
    g_p2[p] = n2;
  } else {           // B: [bh bh bl bl]
    s[0]=hx; s[1]=hy; s[2]=hz;   s[3]=hx; s[4]=hy; s[5]=hz;
    s[6]=lx; s[7]=ly; s[8]=lz;   s[9]=lx; s[10]=ly; s[11]=lz;
    g_g2[p] = n2;
  }
  s[12] = 0; s[13] = 0; s[14] = 0; s[15] = 0;

  uint4 u0, u1;
  u0.x = (unsigned)s[0]  | ((unsigned)s[1]  << 16);
  u0.y = (unsigned)s[2]  | ((unsigned)s[3]  << 16);
  u0.z = (unsigned)s[4]  | ((unsigned)s[5]  << 16);
  u0.w = (unsigned)s[6]  | ((unsigned)s[7]  << 16);
  u1.x = (unsigned)s[8]  | ((unsigned)s[9]  << 16);
  u1.y = (unsigned)s[10] | ((unsigned)s[11] << 16);
  u1.z = (unsigned)s[12] | ((unsigned)s[13] << 16);
  u1.w = (unsigned)s[14] | ((unsigned)s[15] << 16);
  uint4* dst = (uint4*)((side ? g_bpk : g_apk) + (size_t)p * 16);
  dst[0] = u0; dst[1] = u1;
}

__global__ __launch_bounds__(TPB, 4) void cham_mfma() {
  const int ct = blockIdx.x, rt = blockIdx.y, b = blockIdx.z;
  const int t = threadIdx.x, lane = t & 63, w = t >> 6;
  const int l15 = lane & 15, lg = lane >> 4;     // lane group 0..3
  const int kh = lg & 1;                         // payload half index

  const int row0 = rt * TILE + w * 64;           // wave's 64-row stripe
  const int col0 = ct * TILE;

  const unsigned short* Ap = g_apk + (size_t)b * Nc * 16;
  const unsigned short* Bp = g_bpk + (size_t)b * Nc * 16;
  const float* P2 = g_p2 + (size_t)b * Nc;
  const float* G2 = g_g2 + (size_t)b * Nc;

  // ---- LDS staging: A-tile, B-tile (payload halves split), g2 ----
  __shared__ __align__(16) unsigned short lds_a[2][TILE][8];  // 8 KB
  __shared__ __align__(16) unsigned short lds_b[2][TILE][8];  // 8 KB
  __shared__ float lds_g2[TILE];                              // 1 KB
  {
    const uint4* asrc = (const uint4*)(Ap + (size_t)(rt * TILE + t) * 16);
    uint4 av0 = asrc[0], av1 = asrc[1];
    const uint4* bsrc = (const uint4*)(Bp + (size_t)(col0 + t) * 16);
    uint4 bv0 = bsrc[0], bv1 = bsrc[1];
    *(uint4*)&lds_a[0][t][0] = av0;
    *(uint4*)&lds_a[1][t][0] = av1;
    *(uint4*)&lds_b[0][t][0] = bv0;
    *(uint4*)&lds_b[1][t][0] = bv1;
    lds_g2[t] = G2[col0 + t];
  }

  float p2r[4][4];
  #pragma unroll
  for (int ai = 0; ai < 4; ++ai)
    #pragma unroll
    for (int r = 0; r < 4; ++r)
      p2r[ai][r] = P2[row0 + ai * 16 + lg * 4 + r];   // verified C/D row map

  __syncthreads();

  bf16x8 afr[4];
  #pragma unroll
  for (int ai = 0; ai < 4; ++ai)
    afr[ai] = *(const bf16x8*)&lds_a[kh][w * 64 + ai * 16 + l15][0];

  float g2c[16];
  #pragma unroll
  for (int bi = 0; bi < 16; ++bi)
    g2c[bi] = lds_g2[bi * 16 + l15];                  // verified C/D col map

  const f32x4 zero = {0, 0, 0, 0};
  const float INF = __builtin_inff();
  float racc[4][4], cacc[16];
  #pragma unroll
  for (int ai = 0; ai < 4; ++ai)
    #pragma unroll
    for (int r = 0; r < 4; ++r) racc[ai][r] = INF;
  #pragma unroll
  for (int bi = 0; bi < 16; ++bi) cacc[bi] = INF;

  #pragma unroll
  for (int grp = 0; grp < 4; ++grp) {
    bf16x8 bfr[4];
    #pragma unroll
    for (int k = 0; k < 4; ++k)
      bfr[k] = *(const bf16x8*)&lds_b[kh][(grp * 4 + k) * 16 + l15][0];
    #pragma unroll
    for (int kp = 0; kp < 2; ++kp) {
      const int bi0 = grp * 4 + kp * 2, bi1 = bi0 + 1;
      #pragma unroll
      for (int ai = 0; ai < 4; ++ai) {
        f32x4 d0 = __builtin_amdgcn_mfma_f32_16x16x32_bf16(afr[ai], bfr[kp * 2],     zero, 0, 0, 0);
        f32x4 d1 = __builtin_amdgcn_mfma_f32_16x16x32_bf16(afr[ai], bfr[kp * 2 + 1], zero, 0, 0, 0);
        // row path: min_j (D + g2[j]) — paired min3 (bit-exact reorder)
        racc[ai][0] = min3f(d0[0] + g2c[bi0], d1[0] + g2c[bi1], racc[ai][0]);
        racc[ai][1] = min3f(d0[1] + g2c[bi0], d1[1] + g2c[bi1], racc[ai][1]);
        racc[ai][2] = min3f(d0[2] + g2c[bi0], d1[2] + g2c[bi1], racc[ai][2]);
        racc[ai][3] = min3f(d0[3] + g2c[bi0], d1[3] + g2c[bi1], racc[ai][3]);
        // col path: min_i (D + p2[i])
        cacc[bi0] = min3f(d0[0] + p2r[ai][0], d0[1] + p2r[ai][1], cacc[bi0]);
        cacc[bi0] = min3f(d0[2] + p2r[ai][2], d0[3] + p2r[ai][3], cacc[bi0]);
        cacc[bi1] = min3f(d1[0] + p2r[ai][0], d1[1] + p2r[ai][1], cacc[bi1]);
        cacc[bi1] = min3f(d1[2] + p2r[ai][2], d1[3] + p2r[ai][3], cacc[bi1]);
      }
    }
  }

  // ---- row mins: reduce across 16 cols (lanes sharing lg) ----
  #pragma unroll
  for (int ai = 0; ai < 4; ++ai) {
    #pragma unroll
    for (int r = 0; r < 4; ++r) {
      float v = racc[ai][r];
      v = fminf(v, __shfl_xor(v, 1, 64));
      v = fminf(v, __shfl_xor(v, 2, 64));
      v = fminf(v, __shfl_xor(v, 4, 64));
      v = fminf(v, __shfl_xor(v, 8, 64));
      racc[ai][r] = v;
    }
  }
  if (l15 == 0) {
    unsigned* grow = g_min2 + (size_t)b * Nc + row0;
    #pragma unroll
    for (int ai = 0; ai < 4; ++ai) {
      #pragma unroll
      for (int r = 0; r < 4; ++r) {
        float v = fmaxf(racc[ai][r] + p2r[ai][r], 0.0f);  // + |p|^2, clamp
        atomicMin(grow + ai * 16 + lg * 4 + r, __float_as_uint(v));
      }
    }
  }

  // ---- col mins: fold lane groups, combine 4 waves via LDS ----
  __shared__ float lcol[4][TILE];
  #pragma unroll
  for (int bi = 0; bi < 16; ++bi) {
    float v = cacc[bi];
    v = fminf(v, __shfl_xor(v, 16, 64));
    v = fminf(v, __shfl_xor(v, 32, 64));
    v = v + g2c[bi];                                   // + |g|^2
    if (lane < 16) lcol[w][bi * 16 + l15] = v;
  }
  __syncthreads();
  {
    float v = fminf(fminf(lcol[0][t], lcol[1][t]), fminf(lcol[2][t], lcol[3][t]));
    v = fmaxf(v, 0.0f);                                // clamp BEFORE unsigned min
    atomicMin(g_min2 + (size_t)(Bc + b) * Nc + col0 + t, __float_as_uint(v));
  }
}

__global__ __launch_bounds__(TPB) void reduce_kernel(float* __restrict__ out) {
  const int total = 2 * Bc * Nc;
  float s = 0.0f;
  for (int i = blockIdx.x * TPB + threadIdx.x; i < total; i += gridDim.x * TPB)
    s += __uint_as_float(g_min2[i]);          // already clamped non-negative
  #pragma unroll
  for (int off = 32; off > 0; off >>= 1) s += __shfl_down(s, off, 64);
  __shared__ float wsum[TPB / 64];
  const int lane = threadIdx.x & 63, wid = threadIdx.x >> 6;
  if (lane == 0) wsum[wid] = s;
  __syncthreads();
  if (threadIdx.x == 0) {
    float tot = 0.0f;
    #pragma unroll
    for (int w = 0; w < TPB / 64; ++w) tot += wsum[w];
    atomicAdd(out, tot * (1.0f / (float)(Bc * Nc)));
  }
}

extern "C" void kernel_launch(void* const* d_in, const int* in_sizes, int n_in,
                              void* d_out, int out_size, void* d_ws, size_t ws_size,
                              hipStream_t stream) {
  const float* pred = (const float*)d_in[0];
  const float* gt   = (const float*)d_in[1];
  float* out = (float*)d_out;

  init_kernel<<<(2 * Bc * Nc + TPB - 1) / TPB, TPB, 0, stream>>>(out);
  pack_kernel<<<(2 * Bc * Nc) / TPB, TPB, 0, stream>>>(pred, gt);

  dim3 grid(NT, NT, Bc);   // 16 x 16 x 8 = 2048 blocks
  cham_mfma<<<grid, TPB, 0, stream>>>();

  reduce_kernel<<<64, TPB, 0, stream>>>(out);
}